// Round 11
// baseline (1638.460 us; speedup 1.0000x reference)
//
#include <hip/hip_runtime.h>
#include <math.h>

#define B_ 1024
#define E_ 6

typedef _Float16 half8 __attribute__((ext_vector_type(8)));
typedef float f32x4 __attribute__((ext_vector_type(4)));

__device__ __forceinline__ unsigned short h_bits(_Float16 h) {
    union { _Float16 f; unsigned short u; } c; c.f = h; return c.u;
}

// ---------------------------------------------------------------------------
// Direct-conv weight prep (t1 + c1): fold BN, transpose to [ci][k][co].
// ---------------------------------------------------------------------------
__global__ void prep_w(const float* __restrict__ w, const float* __restrict__ g,
                       float* __restrict__ wout, int CO, int CI, int total) {
    int i = blockIdx.x * 256 + threadIdx.x;
    if (i >= total) return;
    int k = i % 9;
    int t = i / 9;
    int ci = t % CI; t /= CI;
    int co = t % CO;
    int e  = t / CO;
    float s = g[e * CO + co] * (1.0f / sqrtf(1.0f + 1e-5f));
    wout[(((long)(e * CI + ci) * 9 + k) * CO) + co] = w[i] * s;
}

__global__ void prep_b(const float* __restrict__ cb, const float* __restrict__ g,
                       const float* __restrict__ bb, float* __restrict__ bout, int N) {
    int i = blockIdx.x * 256 + threadIdx.x;
    if (i >= N) return;
    float s = g[i] * (1.0f / sqrtf(1.0f + 1e-5f));
    float c = (cb != nullptr) ? cb[i] : 0.0f;
    bout[i] = c * s + bb[i];
}

// ---------------------------------------------------------------------------
// MFMA weight prep: fold BN, split fp16 hi/lo (lo*2048), B-fragment order
// [e][nbg NB][tap 9][chunk NC][plane 2][lane 64][j 8].
// ---------------------------------------------------------------------------
__global__ void prep_wfrag(const float* __restrict__ w, const float* __restrict__ g,
                           _Float16* __restrict__ out, int CI, int CO, int total) {
    int i = blockIdx.x * 256 + threadIdx.x;
    if (i >= total) return;
    const int NC = CI / 32;
    const int NB = CO / 16;
    int j = i & 7;
    int lane = (i >> 3) & 63;
    int rest = i >> 9;
    int chunk = rest % NC; rest /= NC;
    int tap = rest % 9; rest /= 9;
    int nbg = rest % NB;
    int e = rest / NB;
    int co = nbg * 16 + (lane & 15);
    int ci = chunk * 32 + ((lane >> 4) * 8) + j;
    float s = g[e * CO + co] * (1.0f / sqrtf(1.0f + 1e-5f));
    float v = w[(((long)(e * CO + co) * CI + ci) * 9) + tap] * s;
    _Float16 hi = (_Float16)v;
    _Float16 lo = (_Float16)((v - (float)hi) * 2048.0f);
    long perE = (long)NB * 9 * NC * 2 * 512;
    long F0 = ((long)(nbg * 9 + tap) * NC + chunk) * 2;
    long base = (long)e * perE + F0 * 512 + lane * 8 + j;
    out[base] = hi;
    out[base + 512] = lo;
}

// ---------------------------------------------------------------------------
// Fused trunk t1+t2: per 16x16 tile of a 32x32 image, stage x (20x20 halo),
// compute t1 conv(3->32)+relu DIRECTLY into t2's 18x18xPXS40 LDS window
// (real halo px computed, out-of-image px zero), then the proven t2 MFMA
// body (conv 32->32, 2x2 maxpool, 8x8 avgpool) -> rf_in.
// t1 fma order identical to the old conv3x3<3,32,...> instantiation;
// t2 body identical to old conv_mfma_t2 -> bitwise-identical rf_in.
// Saves 128 MB of t1<->t2 HBM round-trip + 3 launches.
// LDS: 4.8K xs + 3.5K w1 + 51.8K window + red = 60.7 KB -> 2 blocks/CU.
// ---------------------------------------------------------------------------
__launch_bounds__(256, 2)
__global__ void conv_trunk(const float* __restrict__ x,
                           const float* __restrict__ w1, const float* __restrict__ b1,
                           const _Float16* __restrict__ wt2, const float* __restrict__ bias2,
                           float* __restrict__ rf) {
    constexpr int PXS = 40;
    __shared__ float xs[3 * 400];      // 20x20 halo'd input, 3 channels
    __shared__ float w1s[864];
    __shared__ float b1s[32];
    __shared__ _Float16 ldsH[18 * 18 * PXS];
    __shared__ _Float16 ldsL[18 * 18 * PXS];
    __shared__ float red[4][32];

    const int tid = threadIdx.x;
    const int wv = tid >> 6, lane = tid & 63;
    const int q = lane >> 4, l15 = lane & 15;
    const int bid = blockIdx.x;
    const int nl = bid >> 2, tile = bid & 3;
    const int ty2 = (tile >> 1) * 16, tx2 = (tile & 1) * 16;

    {   // zero the window: out-of-image halo px must stay zero
        half8 z = {};
        half8* zh = (half8*)ldsH;
        half8* zl = (half8*)ldsL;
        for (int i = tid; i < 18 * 18 * PXS / 8; i += 256) { zh[i] = z; zl[i] = z; }
    }
    for (int i = tid; i < 864; i += 256) w1s[i] = w1[i];
    if (tid < 32) b1s[tid] = b1[tid];
    for (int i = tid; i < 1200; i += 256) {
        int c = i / 400;
        int r = i - c * 400;
        int yy = ty2 + r / 20 - 2, xx = tx2 + r % 20 - 2;
        float v = 0.0f;
        if ((unsigned)yy < 32u && (unsigned)xx < 32u)
            v = x[((long)nl * 3 + c) * 1024 + yy * 32 + xx];
        xs[i] = v;
    }
    __syncthreads();

    // t1 at every in-image window px (18x18 incl. real halo from neighbors)
    for (int p = tid; p < 324; p += 256) {
        int wy = p / 18, wx = p - wy * 18;
        int gy = ty2 + wy - 1, gx = tx2 + wx - 1;
        if ((unsigned)gy < 32u && (unsigned)gx < 32u) {
            float acc[32];
#pragma unroll
            for (int j = 0; j < 32; ++j) acc[j] = b1s[j];
            for (int ci = 0; ci < 3; ++ci)
#pragma unroll
                for (int ky = 0; ky < 3; ++ky)
#pragma unroll
                    for (int kx = 0; kx < 3; ++kx) {
                        float v = xs[ci * 400 + (wy + ky) * 20 + (wx + kx)];
                        const float* wr = &w1s[((ci * 3 + ky) * 3 + kx) * 32];
#pragma unroll
                        for (int j = 0; j < 32; ++j) acc[j] = fmaf(v, wr[j], acc[j]);
                    }
            int fb = (wy * 18 + wx) * PXS;
#pragma unroll
            for (int j = 0; j < 32; ++j) {
                float m = fmaxf(acc[j], 0.0f);
                _Float16 hi = (_Float16)m;
                _Float16 lo = (_Float16)((m - (float)hi) * 2048.0f);
                ldsH[fb + j] = hi;
                ldsL[fb + j] = lo;
            }
        }
    }
    __syncthreads();

    // ---- t2 MFMA body (verbatim from conv_mfma_t2) ----
    f32x4 accH[8], accL[8];
#pragma unroll
    for (int i = 0; i < 8; ++i) { accH[i] = (f32x4){0,0,0,0}; accL[i] = (f32x4){0,0,0,0}; }

#pragma unroll
    for (int ky = 0; ky < 3; ++ky)
#pragma unroll
        for (int kx = 0; kx < 3; ++kx) {
            const int tap = ky * 3 + kx;
            half8 ah[4], al[4];
#pragma unroll
            for (int mb = 0; mb < 4; ++mb) {
                int y = wv * 4 + mb;
                int fi = ((y + ky) * 18 + (l15 + kx)) * PXS + q * 8;
                ah[mb] = *(const half8*)&ldsH[fi];
                al[mb] = *(const half8*)&ldsL[fi];
            }
            half8 bh[2], bl[2];
#pragma unroll
            for (int nb = 0; nb < 2; ++nb) {
                int F0 = (nb * 9 + tap) * 2;
                bh[nb] = ((const half8*)wt2)[(long)F0 * 64 + lane];
                bl[nb] = ((const half8*)wt2)[(long)(F0 + 1) * 64 + lane];
            }
#pragma unroll
            for (int nb = 0; nb < 2; ++nb)
#pragma unroll
                for (int mb = 0; mb < 4; ++mb)
                    accH[mb * 2 + nb] = __builtin_amdgcn_mfma_f32_16x16x32_f16(
                        ah[mb], bh[nb], accH[mb * 2 + nb], 0, 0, 0);
#pragma unroll
            for (int nb = 0; nb < 2; ++nb)
#pragma unroll
                for (int mb = 0; mb < 4; ++mb)
                    accL[mb * 2 + nb] = __builtin_amdgcn_mfma_f32_16x16x32_f16(
                        ah[mb], bl[nb], accL[mb * 2 + nb], 0, 0, 0);
#pragma unroll
            for (int nb = 0; nb < 2; ++nb)
#pragma unroll
                for (int mb = 0; mb < 4; ++mb)
                    accL[mb * 2 + nb] = __builtin_amdgcn_mfma_f32_16x16x32_f16(
                        al[mb], bh[nb], accL[mb * 2 + nb], 0, 0, 0);
        }

    const float inv2048 = 1.0f / 2048.0f;
    float bv[2];
#pragma unroll
    for (int nb = 0; nb < 2; ++nb) bv[nb] = bias2[nb * 16 + l15];
    float avg[2] = {0.0f, 0.0f};
#pragma unroll
    for (int k = 0; k < 2; ++k)
#pragma unroll
        for (int j = 0; j < 2; ++j)
#pragma unroll
            for (int nb = 0; nb < 2; ++nb) {
                float m = -1e30f;
#pragma unroll
                for (int dm = 0; dm < 2; ++dm)
#pragma unroll
                    for (int dr = 0; dr < 2; ++dr) {
                        int a = (2 * k + dm) * 2 + nb;
                        int r = 2 * j + dr;
                        float v = accH[a][r] + accL[a][r] * inv2048 + bv[nb];
                        m = fmaxf(m, v);
                    }
                avg[nb] += fmaxf(m, 0.0f);
            }
#pragma unroll
    for (int nb = 0; nb < 2; ++nb) {
        avg[nb] += __shfl_xor(avg[nb], 16);
        avg[nb] += __shfl_xor(avg[nb], 32);
    }
    if (q == 0) {
        red[wv][l15] = avg[0];
        red[wv][16 + l15] = avg[1];
    }
    __syncthreads();
    if (tid < 32) {
        float s = red[0][tid] + red[1][tid] + red[2][tid] + red[3][tid];
        rf[(long)nl * 128 + tid * 4 + (tile >> 1) * 2 + (tile & 1)] = s * (1.0f / 64.0f);
    }
}

// ---------------------------------------------------------------------------
// FULLY-FUSED expert + head: c1(3->32,pool) -> c2(32->64) -> c3(64->64,pool)
// -> c4(64->128) -> c5(128->128) -> GAP -> fc1(128,relu) -> fc2(10).
// Grid = E_*B_ blocks (e = blockIdx>>10), 512 threads (8 waves = 2/SIMD,
// the best-measured config; 16-wave R10 attempt spilled and lost MFMA
// fragment reuse).  bufB/bufC at PXS=32 (R7's empirically lower-conflict
// layout: 95M vs 155M at PXS=40).  All intermediates LDS-resident.
// LDS pool 155,520 B, time-aliased:
//   region0 [0,25920) f16  : c1-out window -> bufB (c3-out) -> fe/fv (head)
//   region1 [25920,77760)  : xs+w1+b1 -> A64 (c2-out) -> bufC (c4-out)
// ---------------------------------------------------------------------------
__launch_bounds__(512, 2)
__global__ void conv_expert(const float* __restrict__ x,
                            const float* __restrict__ w1b, const float* __restrict__ b1b_,
                            const _Float16* __restrict__ wt2b, const float* __restrict__ b2b_,
                            const _Float16* __restrict__ wt3b, const float* __restrict__ b3b_,
                            const _Float16* __restrict__ wt4b, const float* __restrict__ b4b_,
                            const _Float16* __restrict__ wt5b, const float* __restrict__ b5b_,
                            const float* __restrict__ fwb, const float* __restrict__ fbb,
                            const float* __restrict__ cwb, const float* __restrict__ cbb,
                            float* __restrict__ logitsE) {
    __shared__ _Float16 pool[77760];
    _Float16* c2H = pool;                  // [324][40]
    _Float16* c2L = pool + 12960;
    _Float16* BH  = pool;                  // [2][100][32] (alias region0)
    _Float16* BL  = pool + 6400;
    float* xs  = (float*)(pool + 25920);               // 3468 floats
    float* w1s = (float*)(pool + 25920 + 6936);        // 864
    float* b1s = (float*)(pool + 25920 + 6936 + 1728); // 32
    _Float16* AH = pool + 25920;           // [2][324][40]
    _Float16* AL = pool + 51840;
    _Float16* CH = pool + 25920;           // [4][100][32] (alias region1)
    _Float16* CL = pool + 38720;

    const int tid = threadIdx.x;
    const int wv = tid >> 6, lane = tid & 63;
    const int q = lane >> 4, l15 = lane & 15;
    const int rg = wv >> 1, ch2 = wv & 1;
    const int e = blockIdx.x >> 10;
    const int n = blockIdx.x & 1023;
    const float inv2048 = 1.0f / 2048.0f;

    const float* w1 = w1b + e * 864;
    const float* b1 = b1b_ + e * 32;
    const _Float16* wt2 = wt2b + (size_t)e * 36864;
    const float* b2 = b2b_ + e * 64;
    const _Float16* wt3 = wt3b + (size_t)e * 73728;
    const float* b3 = b3b_ + e * 64;
    const _Float16* wt4 = wt4b + (size_t)e * 147456;
    const float* b4 = b4b_ + e * 128;
    const _Float16* wt5 = wt5b + (size_t)e * 294912;
    const float* b5 = b5b_ + e * 128;
    const float* fw = fwb + (size_t)e * 16384;
    const float* fb = fbb + e * 128;
    const float* cw = cwb + (size_t)e * 1280;
    const float* cb = cbb + e * 10;
    float* outl = logitsE + (size_t)e * (B_ * 10);

    // ---- P0: zero c1-out window; stage x + c1 weights ----
    {
        half8 z = {};
        half8* zp = (half8*)pool;          // region0 = 3240 half8
        for (int i = tid; i < 3240; i += 512) zp[i] = z;
    }
    for (int i = tid; i < 864; i += 512) w1s[i] = w1[i];
    if (tid < 32) b1s[tid] = b1[tid];
    for (int i = tid; i < 3 * 1156; i += 512) {
        int c = i / 1156;
        int r = i - c * 1156;
        int yy = r / 34 - 1, xx = r % 34 - 1;
        float v = 0.0f;
        if ((unsigned)yy < 32u && (unsigned)xx < 32u)
            v = x[((long)n * 3 + c) * 1024 + yy * 32 + xx];
        xs[i] = v;
    }
    __syncthreads();

    // ---- P1: c1 direct conv + relu + maxpool -> c1-out window interior ----
    {
        const int pix = tid & 255;
        const int py1 = pix >> 4, px1 = pix & 15;
        const int coh = tid >> 8;
#pragma unroll
        for (int cg = 0; cg < 2; ++cg) {
            const int cog = coh * 2 + cg;
            float a[4][8];
#pragma unroll
            for (int j = 0; j < 8; ++j) {
                float bvv = b1s[cog * 8 + j];
#pragma unroll
                for (int p = 0; p < 4; ++p) a[p][j] = bvv;
            }
            for (int ci = 0; ci < 3; ++ci) {
                float patch[16];
#pragma unroll
                for (int r = 0; r < 4; ++r)
#pragma unroll
                    for (int cpx = 0; cpx < 4; ++cpx)
                        patch[r * 4 + cpx] = xs[ci * 1156 + (2 * py1 + r) * 34 + (2 * px1 + cpx)];
#pragma unroll
                for (int ky = 0; ky < 3; ++ky)
#pragma unroll
                    for (int kx = 0; kx < 3; ++kx) {
                        const float* wr = &w1s[((ci * 3 + ky) * 3 + kx) * 32 + cog * 8];
#pragma unroll
                        for (int j = 0; j < 8; ++j) {
                            float wvv = wr[j];
#pragma unroll
                            for (int dy = 0; dy < 2; ++dy)
#pragma unroll
                                for (int dx = 0; dx < 2; ++dx)
                                    a[dy * 2 + dx][j] =
                                        fmaf(patch[(dy + ky) * 4 + (dx + kx)], wvv,
                                             a[dy * 2 + dx][j]);
                        }
                    }
            }
            int fibase = ((py1 + 1) * 18 + (px1 + 1)) * 40 + cog * 8;
#pragma unroll
            for (int j = 0; j < 8; ++j) {
                float m = fmaxf(fmaxf(a[0][j], a[1][j]), fmaxf(a[2][j], a[3][j]));
                m = fmaxf(m, 0.0f);
                _Float16 hi = (_Float16)m;
                _Float16 lo = (_Float16)((m - (float)hi) * 2048.0f);
                c2H[fibase + j] = hi;
                c2L[fibase + j] = lo;
            }
        }
    }
    __syncthreads();

    // ---- P2: zero A64 halo ring (xs/w1s dead); c2 MFMA; epilogue -> A64 ----
    for (int u = tid; u < 2 * 68 * 5; u += 512) {
        int g = u % 5;
        int t2 = u / 5;
        int ck = t2 / 68;
        int rp = t2 % 68;
        int wy, wx;
        if (rp < 18) { wy = 0; wx = rp; }
        else if (rp < 36) { wy = 17; wx = rp - 18; }
        else if (rp < 52) { wy = rp - 35; wx = 0; }
        else { wy = rp - 51; wx = 17; }
        int fi = ck * 12960 + (wy * 18 + wx) * 40 + g * 8;
        *(uint4*)(&AH[fi]) = make_uint4(0, 0, 0, 0);
        *(uint4*)(&AL[fi]) = make_uint4(0, 0, 0, 0);
    }

    f32x4 accH[8], accL[8];
#pragma unroll
    for (int i = 0; i < 8; ++i) { accH[i] = (f32x4){0,0,0,0}; accL[i] = (f32x4){0,0,0,0}; }

#pragma unroll
    for (int ky = 0; ky < 3; ++ky)
#pragma unroll
        for (int kx = 0; kx < 3; ++kx) {
            const int tap = ky * 3 + kx;
            half8 ah[4], al[4];
#pragma unroll
            for (int mb = 0; mb < 4; ++mb) {
                int y = rg * 4 + mb;
                int fi = ((y + ky) * 18 + (l15 + kx)) * 40 + q * 8;
                ah[mb] = *(const half8*)&c2H[fi];
                al[mb] = *(const half8*)&c2L[fi];
            }
            half8 bh[2], bl[2];
#pragma unroll
            for (int nb = 0; nb < 2; ++nb) {
                int nbg = ch2 * 2 + nb;
                int F0 = (nbg * 9 + tap) * 2;
                bh[nb] = ((const half8*)wt2)[(long)F0 * 64 + lane];
                bl[nb] = ((const half8*)wt2)[(long)(F0 + 1) * 64 + lane];
            }
#pragma unroll
            for (int nb = 0; nb < 2; ++nb)
#pragma unroll
                for (int mb = 0; mb < 4; ++mb)
                    accH[mb * 2 + nb] = __builtin_amdgcn_mfma_f32_16x16x32_f16(
                        ah[mb], bh[nb], accH[mb * 2 + nb], 0, 0, 0);
#pragma unroll
            for (int nb = 0; nb < 2; ++nb)
#pragma unroll
                for (int mb = 0; mb < 4; ++mb)
                    accL[mb * 2 + nb] = __builtin_amdgcn_mfma_f32_16x16x32_f16(
                        ah[mb], bl[nb], accL[mb * 2 + nb], 0, 0, 0);
#pragma unroll
            for (int nb = 0; nb < 2; ++nb)
#pragma unroll
                for (int mb = 0; mb < 4; ++mb)
                    accL[mb * 2 + nb] = __builtin_amdgcn_mfma_f32_16x16x32_f16(
                        al[mb], bh[nb], accL[mb * 2 + nb], 0, 0, 0);
        }
    // c2 epilogue: relu -> split fp16 -> A64 interior (chunk = ch2)
    {
        float bv[2];
#pragma unroll
        for (int nb = 0; nb < 2; ++nb) bv[nb] = b2[ch2 * 32 + nb * 16 + l15];
#pragma unroll
        for (int mb = 0; mb < 4; ++mb) {
            int y = rg * 4 + mb;
#pragma unroll
            for (int r = 0; r < 4; ++r) {
                int p = (y + 1) * 18 + (q * 4 + r + 1);
#pragma unroll
                for (int nb = 0; nb < 2; ++nb) {
                    float v = accH[mb * 2 + nb][r] + accL[mb * 2 + nb][r] * inv2048 + bv[nb];
                    v = fmaxf(v, 0.0f);
                    _Float16 hi = (_Float16)v;
                    _Float16 lo = (_Float16)((v - (float)hi) * 2048.0f);
                    int fi = ch2 * 12960 + p * 40 + nb * 16 + l15;
                    AH[fi] = hi;
                    AL[fi] = lo;
                }
            }
        }
    }
    __syncthreads();

    // ---- P3: c3 MFMA (reads A64, 2 chunks, zero staging) ----
#pragma unroll
    for (int i = 0; i < 8; ++i) { accH[i] = (f32x4){0,0,0,0}; accL[i] = (f32x4){0,0,0,0}; }

    for (int c = 0; c < 2; ++c) {
#pragma unroll
        for (int ky = 0; ky < 3; ++ky)
#pragma unroll
            for (int kx = 0; kx < 3; ++kx) {
                const int tap = ky * 3 + kx;
                half8 ah[4], al[4];
#pragma unroll
                for (int mb = 0; mb < 4; ++mb) {
                    int y = rg * 4 + mb;
                    int fi = c * 12960 + ((y + ky) * 18 + (l15 + kx)) * 40 + q * 8;
                    ah[mb] = *(const half8*)&AH[fi];
                    al[mb] = *(const half8*)&AL[fi];
                }
                half8 bh[2], bl[2];
#pragma unroll
                for (int nb = 0; nb < 2; ++nb) {
                    int nbg = ch2 * 2 + nb;
                    int F0 = ((nbg * 9 + tap) * 2 + c) * 2;
                    bh[nb] = ((const half8*)wt3)[(long)F0 * 64 + lane];
                    bl[nb] = ((const half8*)wt3)[(long)(F0 + 1) * 64 + lane];
                }
#pragma unroll
                for (int nb = 0; nb < 2; ++nb)
#pragma unroll
                    for (int mb = 0; mb < 4; ++mb)
                        accH[mb * 2 + nb] = __builtin_amdgcn_mfma_f32_16x16x32_f16(
                            ah[mb], bh[nb], accH[mb * 2 + nb], 0, 0, 0);
#pragma unroll
                for (int nb = 0; nb < 2; ++nb)
#pragma unroll
                    for (int mb = 0; mb < 4; ++mb)
                        accL[mb * 2 + nb] = __builtin_amdgcn_mfma_f32_16x16x32_f16(
                            ah[mb], bl[nb], accL[mb * 2 + nb], 0, 0, 0);
#pragma unroll
                for (int nb = 0; nb < 2; ++nb)
#pragma unroll
                    for (int mb = 0; mb < 4; ++mb)
                        accL[mb * 2 + nb] = __builtin_amdgcn_mfma_f32_16x16x32_f16(
                            al[mb], bh[nb], accL[mb * 2 + nb], 0, 0, 0);
            }
    }
    __syncthreads();   // all A64 reads done (region1 becomes bufC)

    // ---- P4: zero bufB + bufC halo rings; c3 epilogue (maxpool) -> bufB ----
    for (int u = tid; u < 2 * 36 * 4; u += 512) {
        int g = u & 3;
        int t2 = u >> 2;
        int ck = t2 / 36;
        int rp = t2 % 36;
        int wy, wx;
        if (rp < 10) { wy = 0; wx = rp; }
        else if (rp < 20) { wy = 9; wx = rp - 10; }
        else if (rp < 28) { wy = rp - 19; wx = 0; }
        else { wy = rp - 27; wx = 9; }
        int fi = ck * 3200 + (wy * 10 + wx) * 32 + g * 8;
        *(uint4*)(&BH[fi]) = make_uint4(0, 0, 0, 0);
        *(uint4*)(&BL[fi]) = make_uint4(0, 0, 0, 0);
    }
    for (int u = tid; u < 4 * 36 * 4; u += 512) {
        int g = u & 3;
        int t2 = u >> 2;
        int ck = t2 / 36;
        int rp = t2 % 36;
        int wy, wx;
        if (rp < 10) { wy = 0; wx = rp; }
        else if (rp < 20) { wy = 9; wx = rp - 10; }
        else if (rp < 28) { wy = rp - 19; wx = 0; }
        else { wy = rp - 27; wx = 9; }
        int fi = ck * 3200 + (wy * 10 + wx) * 32 + g * 8;
        *(uint4*)(&CH[fi]) = make_uint4(0, 0, 0, 0);
        *(uint4*)(&CL[fi]) = make_uint4(0, 0, 0, 0);
    }
    {
        float bv[2];
#pragma unroll
        for (int nb = 0; nb < 2; ++nb) bv[nb] = b3[ch2 * 32 + nb * 16 + l15];
#pragma unroll
        for (int k = 0; k < 2; ++k)
#pragma unroll
            for (int j = 0; j < 2; ++j) {
                int yy = rg * 2 + k;       // pooled row 0..7
                int xx = q * 2 + j;        // pooled col 0..7
                int p = (yy + 1) * 10 + (xx + 1);
#pragma unroll
                for (int nb = 0; nb < 2; ++nb) {
                    float m = -1e30f;
#pragma unroll
                    for (int dm = 0; dm < 2; ++dm)
#pragma unroll
                        for (int dr = 0; dr < 2; ++dr) {
                            int a = (2 * k + dm) * 2 + nb;
                            int r = 2 * j + dr;
                            float v = accH[a][r] + accL[a][r] * inv2048 + bv[nb];
                            m = fmaxf(m, v);
                        }
                    m = fmaxf(m, 0.0f);
                    _Float16 hi = (_Float16)m;
                    _Float16 lo = (_Float16)((m - (float)hi) * 2048.0f);
                    int fi = ch2 * 3200 + p * 32 + nb * 16 + l15;
                    BH[fi] = hi;
                    BL[fi] = lo;
                }
            }
    }
    __syncthreads();

    // ---- P5: c4 MFMA (reads bufB); epilogue -> bufC interior ----
#pragma unroll
    for (int i = 0; i < 4; ++i) { accH[i] = (f32x4){0,0,0,0}; accL[i] = (f32x4){0,0,0,0}; }

    for (int c = 0; c < 2; ++c) {
#pragma unroll
        for (int ky = 0; ky < 3; ++ky)
#pragma unroll
            for (int kx = 0; kx < 3; ++kx) {
                const int tap = ky * 3 + kx;
                half8 ah[4], al[4];
#pragma unroll
                for (int mb = 0; mb < 4; ++mb) {
                    int m = mb * 16 + l15;
                    int p = ((m >> 3) + ky) * 10 + ((m & 7) + kx);
                    int fi = c * 3200 + p * 32 + q * 8;
                    ah[mb] = *(const half8*)&BH[fi];
                    al[mb] = *(const half8*)&BL[fi];
                }
                half8 bh, bl;
                {
                    int F0 = ((wv * 9 + tap) * 2 + c) * 2;
                    bh = ((const half8*)wt4)[(long)F0 * 64 + lane];
                    bl = ((const half8*)wt4)[(long)(F0 + 1) * 64 + lane];
                }
#pragma unroll
                for (int mb = 0; mb < 4; ++mb)
                    accH[mb] = __builtin_amdgcn_mfma_f32_16x16x32_f16(ah[mb], bh, accH[mb], 0, 0, 0);
#pragma unroll
                for (int mb = 0; mb < 4; ++mb)
                    accL[mb] = __builtin_amdgcn_mfma_f32_16x16x32_f16(ah[mb], bl, accL[mb], 0, 0, 0);
#pragma unroll
                for (int mb = 0; mb < 4; ++mb)
                    accL[mb] = __builtin_amdgcn_mfma_f32_16x16x32_f16(al[mb], bh, accL[mb], 0, 0, 0);
            }
    }
    {
        float bv = b4[wv * 16 + l15];
#pragma unroll
        for (int mb = 0; mb < 4; ++mb)
#pragma unroll
            for (int r = 0; r < 4; ++r) {
                int px = mb * 16 + q * 4 + r;
                int p = ((px >> 3) + 1) * 10 + ((px & 7) + 1);
                float v = accH[mb][r] + accL[mb][r] * inv2048 + bv;
                v = fmaxf(v, 0.0f);
                _Float16 hi = (_Float16)v;
                _Float16 lo = (_Float16)((v - (float)hi) * 2048.0f);
                int fi = (wv >> 1) * 3200 + p * 32 + (wv & 1) * 16 + l15;
                CH[fi] = hi;
                CL[fi] = lo;
            }
    }
    __syncthreads();

    // ---- P6: c5 MFMA (reads bufC, 4 chunks); GAP -> fe (LDS, region0) ----
#pragma unroll
    for (int i = 0; i < 4; ++i) { accH[i] = (f32x4){0,0,0,0}; accL[i] = (f32x4){0,0,0,0}; }

    for (int c = 0; c < 4; ++c) {
#pragma unroll
        for (int ky = 0; ky < 3; ++ky)
#pragma unroll
            for (int kx = 0; kx < 3; ++kx) {
                const int tap = ky * 3 + kx;
                half8 ah[4], al[4];
#pragma unroll
                for (int mb = 0; mb < 4; ++mb) {
                    int m = mb * 16 + l15;
                    int p = ((m >> 3) + ky) * 10 + ((m & 7) + kx);
                    int fi = c * 3200 + p * 32 + q * 8;
                    ah[mb] = *(const half8*)&CH[fi];
                    al[mb] = *(const half8*)&CL[fi];
                }
                half8 bh, bl;
                {
                    int F0 = ((wv * 9 + tap) * 4 + c) * 2;
                    bh = ((const half8*)wt5)[(long)F0 * 64 + lane];
                    bl = ((const half8*)wt5)[(long)(F0 + 1) * 64 + lane];
                }
#pragma unroll
                for (int mb = 0; mb < 4; ++mb)
                    accH[mb] = __builtin_amdgcn_mfma_f32_16x16x32_f16(ah[mb], bh, accH[mb], 0, 0, 0);
#pragma unroll
                for (int mb = 0; mb < 4; ++mb)
                    accL[mb] = __builtin_amdgcn_mfma_f32_16x16x32_f16(ah[mb], bl, accL[mb], 0, 0, 0);
#pragma unroll
                for (int mb = 0; mb < 4; ++mb)
                    accL[mb] = __builtin_amdgcn_mfma_f32_16x16x32_f16(al[mb], bh, accL[mb], 0, 0, 0);
            }
    }
    // GAP: each wave owns 16 co; write feat vector into LDS (region0 dead)
    float* fe = (float*)pool;
    float* fv = fe + 128;
    {
        float bv = b5[wv * 16 + l15];
        float s = 0.0f;
#pragma unroll
        for (int mb = 0; mb < 4; ++mb)
#pragma unroll
            for (int r = 0; r < 4; ++r) {
                float v = accH[mb][r] + accL[mb][r] * inv2048 + bv;
                s += fmaxf(v, 0.0f);
            }
        s += __shfl_xor(s, 16);
        s += __shfl_xor(s, 32);
        if (lane < 16) fe[wv * 16 + l15] = s * (1.0f / 64.0f);
    }
    __syncthreads();

    // ---- P7: fused head: fc1(128,relu) -> fc2(10) -> logitsE ----
    if (tid < 128) {
        const float* wr = fw + tid * 128;
        float a = fb[tid];
#pragma unroll 8
        for (int k = 0; k < 128; ++k) a = fmaf(fe[k], wr[k], a);
        fv[tid] = fmaxf(a, 0.0f);
    }
    __syncthreads();
    if (tid < 10) {
        const float* cr = cw + tid * 128;
        float a2 = cb[tid];
#pragma unroll 8
        for (int k = 0; k < 128; ++k) a2 = fmaf(fv[k], cr[k], a2);
        outl[(size_t)n * 10 + tid] = a2;
    }
}

// FC (trunk)
template <int I, int O, bool RELU>
__global__ void fc_k(const float* __restrict__ in, const float* __restrict__ W,
                     const float* __restrict__ bias, float* __restrict__ out) {
    int g = blockIdx.x * 256 + threadIdx.x;
    if (g >= B_ * O) return;
    int n = g / O;
    int o = g - n * O;
    const float* ip = in + (long)n * I;
    const float* wp = W + (long)o * I;
    float a = bias[o];
#pragma unroll 8
    for (int k = 0; k < I; ++k) a = fmaf(ip[k], wp[k], a);
    if (RELU) a = fmaxf(a, 0.0f);
    out[g] = a;
}

// ---------------------------------------------------------------------------
// conf + balanced + top-2 candidates (one thread per sample).
// ---------------------------------------------------------------------------
__global__ void conf_bal_k(const float* __restrict__ logitsE, const float* __restrict__ gate,
                           const float* __restrict__ ema, float* __restrict__ balanced,
                           unsigned char* __restrict__ cand) {
    int b = blockIdx.x * 256 + threadIdx.x;
    if (b >= B_) return;
    float bal[E_];
#pragma unroll
    for (int e = 0; e < E_; ++e) {
        const float* lp = logitsE + ((long)e * B_ + b) * 10;
        float m = lp[0];
#pragma unroll
        for (int k = 1; k < 10; ++k) m = fmaxf(m, lp[k]);
        float s = 0.0f;
#pragma unroll
        for (int k = 0; k < 10; ++k) s += expf(lp[k] - m);
        float ls = m + logf(s);
        float conf = 0.0f;
#pragma unroll
        for (int k = 0; k < 10; ++k) {
            float pp = expf(lp[k] - ls);
            conf += pp * logf(pp + 1e-12f);
        }
        float em = ema[e];
        float boost = (em < 0.05f) ? (0.05f - em) * 10.0f : 0.0f;
        bal[e] = 0.7f * gate[b * E_ + e] + 0.3f * conf + boost - 2.0f * em;
        balanced[b * E_ + e] = bal[e];
    }
    int i0 = 0;
    float m0 = bal[0];
#pragma unroll
    for (int e = 1; e < E_; ++e)
        if (bal[e] > m0) { m0 = bal[e]; i0 = e; }
    int i1 = -1;
    float m1 = -1e38f;
#pragma unroll
    for (int e = 0; e < E_; ++e)
        if (e != i0 && bal[e] > m1) { m1 = bal[e]; i1 = e; }
    cand[b] = (unsigned char)(i0 | (i1 << 3));
}

// ---------------------------------------------------------------------------
// Sequential greedy capacity dispatch — scalarized.
// ---------------------------------------------------------------------------
__global__ void dispatch_k(const unsigned char* __restrict__ cand, int* __restrict__ chosen) {
    int lane = threadIdx.x;
    unsigned long long L = 0;
    for (int r = 0; r < 16; ++r) {
        unsigned int v = cand[r * 64 + lane];
        int ch = 0;
        for (int q2 = 0; q2 < 64; ++q2) {
            unsigned int s = (unsigned int)__builtin_amdgcn_readlane((int)v, q2);
            unsigned int i0 = s & 7u;
            unsigned int i1 = (s >> 3) & 7u;
            unsigned int a0 = (unsigned int)(L >> (i0 * 10)) & 1023u;
            unsigned int a1 = (unsigned int)(L >> (i1 * 10)) & 1023u;
            unsigned int fb = (a1 < a0) ? i1 : i0;
            unsigned int c = (a0 < 192u) ? i0 : ((a1 < 192u) ? i1 : fb);
            if (lane == q2) ch = (int)c;
            L += 1ull << (c * 10);
        }
        chosen[r * 64 + lane] = ch;
    }
}

__global__ void final_k(const float* __restrict__ logitsE, const int* __restrict__ chosen,
                        float* __restrict__ out) {
    int b = blockIdx.x * 256 + threadIdx.x;
    if (b >= B_) return;
    int c = chosen[b];
    const float w = 1.0f / (1.0f + 1e-12f);
    const float* lp = logitsE + ((long)c * B_ + b) * 10;
#pragma unroll
    for (int k = 0; k < 10; ++k) out[b * 10 + k] = lp[k] * w;
    float* Dp = out + B_ * 10 + B_ * E_ + b * E_;
#pragma unroll
    for (int e = 0; e < E_; ++e) Dp[e] = (e == c) ? 1.0f : 0.0f;
}

// ---------------------------------------------------------------------------
extern "C" void kernel_launch(void* const* d_in, const int* in_sizes, int n_in,
                              void* d_out, int out_size, void* d_ws, size_t ws_size,
                              hipStream_t stream) {
    (void)in_sizes; (void)n_in; (void)out_size; (void)ws_size;
    const float* x     = (const float*)d_in[0];
    const float* t_c1w = (const float*)d_in[1];
    const float* t_b1g = (const float*)d_in[2];
    const float* t_b1b = (const float*)d_in[3];
    const float* t_c2w = (const float*)d_in[4];
    const float* t_b2g = (const float*)d_in[5];
    const float* t_b2b = (const float*)d_in[6];
    const float* t_fcw = (const float*)d_in[7];
    const float* t_fcb = (const float*)d_in[8];
    const float* g1w   = (const float*)d_in[9];
    const float* g1b   = (const float*)d_in[10];
    const float* g2w   = (const float*)d_in[11];
    const float* g2b   = (const float*)d_in[12];
    const float* e_c1w = (const float*)d_in[13];
    const float* e_c1b = (const float*)d_in[14];
    const float* e_b1g = (const float*)d_in[15];
    const float* e_b1b = (const float*)d_in[16];
    const float* e_c2w = (const float*)d_in[17];
    const float* e_c2b = (const float*)d_in[18];
    const float* e_b2g = (const float*)d_in[19];
    const float* e_b2b = (const float*)d_in[20];
    const float* e_c3w = (const float*)d_in[21];
    const float* e_c3b = (const float*)d_in[22];
    const float* e_b3g = (const float*)d_in[23];
    const float* e_b3b = (const float*)d_in[24];
    const float* e_c4w = (const float*)d_in[25];
    const float* e_c4b = (const float*)d_in[26];
    const float* e_b4g = (const float*)d_in[27];
    const float* e_b4b = (const float*)d_in[28];
    const float* e_c5w = (const float*)d_in[29];
    const float* e_c5b = (const float*)d_in[30];
    const float* e_b5g = (const float*)d_in[31];
    const float* e_b5b = (const float*)d_in[32];
    const float* e_fw  = (const float*)d_in[33];
    const float* e_fb  = (const float*)d_in[34];
    const float* e_cw  = (const float*)d_in[35];
    const float* e_cb  = (const float*)d_in[36];
    const float* ema   = (const float*)d_in[37];
    float* out = (float*)d_out;
    float* ws  = (float*)d_ws;

    // workspace layout — ALL offsets in FLOAT units.
    size_t o = 0;
    float* rf_in   = ws + o; o += B_ * 128;
    float* rf      = ws + o; o += B_ * 64;
    float* gv      = ws + o; o += B_ * 32;
    float* gate    = ws + o; o += B_ * E_;
    float* logitsE = ws + o; o += E_ * B_ * 10;
    int*   chosen  = (int*)(ws + o); o += B_;
    unsigned char* cand = (unsigned char*)(ws + o); o += 256;
    float* wt_t1 = ws + o; o += 864;
    float* bt_t1 = ws + o; o += 32;
    float* bt_t2 = ws + o; o += 32;
    float* wt_c1 = ws + o; o += 6 * 864;
    float* bt_c1 = ws + o; o += 6 * 32;
    float* bt_c2 = ws + o; o += 6 * 64;
    float* bt_c3 = ws + o; o += 6 * 64;
    float* bt_c4 = ws + o; o += 6 * 128;
    float* bt_c5 = ws + o; o += 6 * 128;
    _Float16* wfrag_t2 = (_Float16*)(ws + o); o += 9216;
    _Float16* wfrag_c2 = (_Float16*)(ws + o); o += 110592;
    _Float16* wfrag_c3 = (_Float16*)(ws + o); o += 221184;
    _Float16* wfrag_c4 = (_Float16*)(ws + o); o += 442368;
    _Float16* wfrag_c5 = (_Float16*)(ws + o); o += 884736;

    auto gsz = [](int n) { return (n + 255) / 256; };
    // ---- weight prep ----
    prep_w<<<gsz(864), 256, 0, stream>>>(t_c1w, t_b1g, wt_t1, 32, 3, 864);
    prep_b<<<1, 256, 0, stream>>>(nullptr, t_b1g, t_b1b, bt_t1, 32);
    prep_wfrag<<<gsz(9216), 256, 0, stream>>>(t_c2w, t_b2g, wfrag_t2, 32, 32, 9216);
    prep_b<<<1, 256, 0, stream>>>(nullptr, t_b2g, t_b2b, bt_t2, 32);
    prep_w<<<gsz(5184), 256, 0, stream>>>(e_c1w, e_b1g, wt_c1, 32, 3, 5184);
    prep_b<<<1, 256, 0, stream>>>(e_c1b, e_b1g, e_b1b, bt_c1, 192);
    prep_wfrag<<<gsz(110592), 256, 0, stream>>>(e_c2w, e_b2g, wfrag_c2, 32, 64, 110592);
    prep_b<<<2, 256, 0, stream>>>(e_c2b, e_b2g, e_b2b, bt_c2, 384);
    prep_wfrag<<<gsz(221184), 256, 0, stream>>>(e_c3w, e_b3g, wfrag_c3, 64, 64, 221184);
    prep_b<<<2, 256, 0, stream>>>(e_c3b, e_b3g, e_b3b, bt_c3, 384);
    prep_wfrag<<<gsz(442368), 256, 0, stream>>>(e_c4w, e_b4g, wfrag_c4, 64, 128, 442368);
    prep_b<<<3, 256, 0, stream>>>(e_c4b, e_b4g, e_b4b, bt_c4, 768);
    prep_wfrag<<<gsz(884736), 256, 0, stream>>>(e_c5w, e_b5g, wfrag_c5, 128, 128, 884736);
    prep_b<<<3, 256, 0, stream>>>(e_c5b, e_b5g, e_b5b, bt_c5, 768);

    // ---- routing trunk: fused t1+t2 (single launch), then FCs ----
    conv_trunk<<<B_ * 4, 256, 0, stream>>>(x, wt_t1, bt_t1, wfrag_t2, bt_t2, rf_in);
    fc_k<128, 64, true><<<256, 256, 0, stream>>>(rf_in, t_fcw, t_fcb, rf);
    fc_k<64, 32, true><<<128, 256, 0, stream>>>(rf, g1w, g1b, gv);
    fc_k<32, 6, false><<<24, 256, 0, stream>>>(gv, g2w, g2b, gate);

    // ---- experts: fully fused c1..c5+GAP+head, all 6 experts, ONE launch ----
    conv_expert<<<E_ * B_, 512, 0, stream>>>(
        x, wt_c1, bt_c1, wfrag_c2, bt_c2, wfrag_c3, bt_c3,
        wfrag_c4, bt_c4, wfrag_c5, bt_c5,
        e_fw, e_fb, e_cw, e_cb, logitsE);

    // ---- scoring, dispatch, combine ----
    float* balanced = out + B_ * 10;
    conf_bal_k<<<4, 256, 0, stream>>>(logitsE, gate, ema, balanced, cand);
    dispatch_k<<<1, 64, 0, stream>>>(cand, chosen);
    final_k<<<4, 256, 0, stream>>>(logitsE, chosen, out);
}

// Round 12
// 1285.257 us; speedup vs baseline: 1.2748x; 1.2748x over previous
//
#include <hip/hip_runtime.h>
#include <math.h>

#define B_ 1024
#define E_ 6

typedef _Float16 half8 __attribute__((ext_vector_type(8)));
typedef float f32x4 __attribute__((ext_vector_type(4)));

__device__ __forceinline__ unsigned short h_bits(_Float16 h) {
    union { _Float16 f; unsigned short u; } c; c.f = h; return c.u;
}
// pack fp32 -> (hi fp16 | lo fp16<<16), lo prescaled by 2048 to avoid fp16 subnormals
__device__ __forceinline__ unsigned int splitpack(float v) {
    _Float16 h = (_Float16)v;
    _Float16 l = (_Float16)((v - (float)h) * 2048.0f);
    return (unsigned int)h_bits(h) | ((unsigned int)h_bits(l) << 16);
}

// ---------------------------------------------------------------------------
// Direct-conv weight prep (t1 + c1): fold BN, transpose to [ci][k][co].
// ---------------------------------------------------------------------------
__global__ void prep_w(const float* __restrict__ w, const float* __restrict__ g,
                       float* __restrict__ wout, int CO, int CI, int total) {
    int i = blockIdx.x * 256 + threadIdx.x;
    if (i >= total) return;
    int k = i % 9;
    int t = i / 9;
    int ci = t % CI; t /= CI;
    int co = t % CO;
    int e  = t / CO;
    float s = g[e * CO + co] * (1.0f / sqrtf(1.0f + 1e-5f));
    wout[(((long)(e * CI + ci) * 9 + k) * CO) + co] = w[i] * s;
}

__global__ void prep_b(const float* __restrict__ cb, const float* __restrict__ g,
                       const float* __restrict__ bb, float* __restrict__ bout, int N) {
    int i = blockIdx.x * 256 + threadIdx.x;
    if (i >= N) return;
    float s = g[i] * (1.0f / sqrtf(1.0f + 1e-5f));
    float c = (cb != nullptr) ? cb[i] : 0.0f;
    bout[i] = c * s + bb[i];
}

// ---------------------------------------------------------------------------
// MFMA weight prep: fold BN, split fp16 hi/lo (lo*2048), B-fragment order
// [e][nbg NB][tap 9][chunk NC][plane 2][lane 64][j 8].
// ---------------------------------------------------------------------------
__global__ void prep_wfrag(const float* __restrict__ w, const float* __restrict__ g,
                           _Float16* __restrict__ out, int CI, int CO, int total) {
    int i = blockIdx.x * 256 + threadIdx.x;
    if (i >= total) return;
    const int NC = CI / 32;
    const int NB = CO / 16;
    int j = i & 7;
    int lane = (i >> 3) & 63;
    int rest = i >> 9;
    int chunk = rest % NC; rest /= NC;
    int tap = rest % 9; rest /= 9;
    int nbg = rest % NB;
    int e = rest / NB;
    int co = nbg * 16 + (lane & 15);
    int ci = chunk * 32 + ((lane >> 4) * 8) + j;
    float s = g[e * CO + co] * (1.0f / sqrtf(1.0f + 1e-5f));
    float v = w[(((long)(e * CO + co) * CI + ci) * 9) + tap] * s;
    _Float16 hi = (_Float16)v;
    _Float16 lo = (_Float16)((v - (float)hi) * 2048.0f);
    long perE = (long)NB * 9 * NC * 2 * 512;
    long F0 = ((long)(nbg * 9 + tap) * NC + chunk) * 2;
    long base = (long)e * perE + F0 * 512 + lane * 8 + j;
    out[base] = hi;
    out[base + 512] = lo;
}

// ---------------------------------------------------------------------------
// Direct conv (trunk t1).  OUTMODE 1 = NHWC packed pair dwords.
// ---------------------------------------------------------------------------
template <int CI, int CO, int H, int TS, int CO_BLK, int CI_CHUNK, bool POOL, int OUTMODE>
__launch_bounds__(256)
__global__ void conv3x3(const float* __restrict__ in, const float* __restrict__ wt,
                        const float* __restrict__ bias, void* __restrict__ outv) {
    constexpr int TD = H / TS;
    constexpr int TILES = TD * TD;
    constexpr int LW = TS + 2;
    constexpr int NPX = POOL ? (TS / 2) * (TS / 2) : TS * TS;
    constexpr int G = 256 / NPX;
    constexpr int NG = CO / CO_BLK;
    constexpr int GPT = NG / G;
    constexpr int COT = GPT * CO_BLK;
    constexpr int NW = POOL ? 4 : 1;
    constexpr int OD = POOL ? TS / 2 : TS;

    __shared__ float lds[CI_CHUNK * LW * LW];

    int bid = blockIdx.x;
    int n = bid / TILES;
    int t = bid % TILES;
    int ty = (t / TD) * TS;
    int tx = (t % TD) * TS;
    int tid = threadIdx.x;
    int px = tid % NPX;
    int cg0 = tid / NPX;
    const int cg0s = __builtin_amdgcn_readfirstlane(cg0);
    int oy = px / OD;
    int ox = px % OD;

    float acc[NW][COT];
#pragma unroll
    for (int g2 = 0; g2 < GPT; ++g2)
#pragma unroll
        for (int j = 0; j < CO_BLK; ++j) {
            float bv = bias[(cg0s + g2 * G) * CO_BLK + j];
#pragma unroll
            for (int p = 0; p < NW; ++p) acc[p][g2 * CO_BLK + j] = bv;
        }

    for (int cc = 0; cc < CI / CI_CHUNK; ++cc) {
        const float* inb = in + ((long)n * CI + cc * CI_CHUNK) * (H * H);
        for (int idx = tid; idx < CI_CHUNK * LW * LW; idx += 256) {
            int ci = idx / (LW * LW);
            int r = idx - ci * (LW * LW);
            int yy = r / LW + ty - 1;
            int xx = r % LW + tx - 1;
            float v = 0.0f;
            if ((unsigned)yy < (unsigned)H && (unsigned)xx < (unsigned)H)
                v = inb[ci * H * H + yy * H + xx];
            lds[idx] = v;
        }
        __syncthreads();

        const float* wbase = wt + ((long)cc * CI_CHUNK) * 9 * CO;
        for (int ci = 0; ci < CI_CHUNK; ++ci) {
#pragma unroll
            for (int ky = 0; ky < 3; ++ky) {
#pragma unroll
                for (int kx = 0; kx < 3; ++kx) {
                    float v[NW];
                    if constexpr (POOL) {
#pragma unroll
                        for (int dy = 0; dy < 2; ++dy)
#pragma unroll
                            for (int dx = 0; dx < 2; ++dx)
                                v[dy * 2 + dx] =
                                    lds[ci * LW * LW + (2 * oy + dy + ky) * LW + (2 * ox + dx + kx)];
                    } else {
                        v[0] = lds[ci * LW * LW + (oy + ky) * LW + (ox + kx)];
                    }
                    const float* wr = wbase + ((ci * 3 + ky) * 3 + kx) * CO + cg0s * CO_BLK;
#pragma unroll
                    for (int g2 = 0; g2 < GPT; ++g2)
#pragma unroll
                        for (int j = 0; j < CO_BLK; ++j) {
                            float wv = wr[g2 * G * CO_BLK + j];
#pragma unroll
                            for (int p = 0; p < NW; ++p)
                                acc[p][g2 * CO_BLK + j] = fmaf(v[p], wv, acc[p][g2 * CO_BLK + j]);
                        }
                }
            }
        }
        __syncthreads();
    }

    if constexpr (OUTMODE == 1) {
        unsigned int* po = (unsigned int*)outv;
        long base;
        if constexpr (POOL) {
            constexpr int HP = H / 2;
            int pp = (ty / 2 + oy) * HP + (tx / 2 + ox);
            base = ((long)n * (HP * HP) + pp) * CO;
        } else {
            int pp = (ty + oy) * H + (tx + ox);
            base = ((long)n * (H * H) + pp) * CO;
        }
#pragma unroll
        for (int g2 = 0; g2 < GPT; ++g2) {
            int cobase = (cg0s + g2 * G) * CO_BLK;
#pragma unroll
            for (int j4 = 0; j4 < CO_BLK; j4 += 4) {
                uint4 u;
                unsigned int* up = (unsigned int*)&u;
#pragma unroll
                for (int jj = 0; jj < 4; ++jj) {
                    int a = g2 * CO_BLK + j4 + jj;
                    float v;
                    if constexpr (POOL)
                        v = fmaxf(fmaxf(acc[0][a], acc[1][a]), fmaxf(acc[2][a], acc[3][a]));
                    else
                        v = acc[0][a];
                    up[jj] = splitpack(fmaxf(v, 0.0f));
                }
                *(uint4*)(po + base + cobase + j4) = u;
            }
        }
    } else {
        float* out = (float*)outv;
        if constexpr (POOL) {
            constexpr int HP = H / 2;
            int py = ty / 2 + oy;
            int pxx = tx / 2 + ox;
#pragma unroll
            for (int g2 = 0; g2 < GPT; ++g2)
#pragma unroll
                for (int j = 0; j < CO_BLK; ++j) {
                    int co = (cg0s + g2 * G) * CO_BLK + j;
                    int a = g2 * CO_BLK + j;
                    float m = fmaxf(fmaxf(acc[0][a], acc[1][a]), fmaxf(acc[2][a], acc[3][a]));
                    out[((long)n * CO + co) * (HP * HP) + py * HP + pxx] = fmaxf(m, 0.0f);
                }
        } else {
            int yy = ty + oy;
            int xx = tx + ox;
#pragma unroll
            for (int g2 = 0; g2 < GPT; ++g2)
#pragma unroll
                for (int j = 0; j < CO_BLK; ++j) {
                    int co = (cg0s + g2 * G) * CO_BLK + j;
                    out[((long)n * CO + co) * (H * H) + yy * H + xx] =
                        fmaxf(acc[0][g2 * CO_BLK + j], 0.0f);
                }
        }
    }
}

// ---------------------------------------------------------------------------
// Trunk t2: MFMA conv 3x3 (32ch->32ch) on a 16x16 tile of a 32x32 image with
// fused 2x2 maxpool AND 8x8 avgpool.  Input packed NHWC [n][1024][32].
// ---------------------------------------------------------------------------
__launch_bounds__(256, 2)
__global__ void conv_mfma_t2(const unsigned int* __restrict__ in,
                             const _Float16* __restrict__ wt,
                             const float* __restrict__ bias,
                             float* __restrict__ rf, int n0) {
    constexpr int PXS = 40;
    __shared__ _Float16 ldsH[18 * 18 * PXS];
    __shared__ _Float16 ldsL[18 * 18 * PXS];
    __shared__ float red[4][32];

    const int tid = threadIdx.x;
    const int wv = tid >> 6, lane = tid & 63;
    const int q = lane >> 4, l15 = lane & 15;
    const int bid = blockIdx.x;
    const int nl = bid >> 2, tile = bid & 3;
    const int ty2 = (tile >> 1) * 16, tx2 = (tile & 1) * 16;

    f32x4 accH[8], accL[8];
#pragma unroll
    for (int i = 0; i < 8; ++i) { accH[i] = (f32x4){0,0,0,0}; accL[i] = (f32x4){0,0,0,0}; }

    for (int u = tid; u < 18 * 18 * 8; u += 256) {
        int cu = u & 7;
        int p = u >> 3;
        int wy = p / 18, wx = p % 18;
        int gy = ty2 + wy - 1, gx = tx2 + wx - 1;
        uint4 w = make_uint4(0, 0, 0, 0);
        if ((unsigned)gy < 32u && (unsigned)gx < 32u)
            w = *(const uint4*)(in + ((long)nl * 1024 + gy * 32 + gx) * 32 + cu * 4);
        unsigned int h01 = (w.x & 0xffffu) | (w.y << 16);
        unsigned int h23 = (w.z & 0xffffu) | (w.w << 16);
        unsigned int l01 = (w.x >> 16) | (w.y & 0xffff0000u);
        unsigned int l23 = (w.z >> 16) | (w.w & 0xffff0000u);
        int fi = (wy * 18 + wx) * PXS + cu * 4;
        *(uint2*)(&ldsH[fi]) = make_uint2(h01, h23);
        *(uint2*)(&ldsL[fi]) = make_uint2(l01, l23);
    }
    __syncthreads();

#pragma unroll
    for (int ky = 0; ky < 3; ++ky)
#pragma unroll
        for (int kx = 0; kx < 3; ++kx) {
            const int tap = ky * 3 + kx;
            half8 ah[4], al[4];
#pragma unroll
            for (int mb = 0; mb < 4; ++mb) {
                int y = wv * 4 + mb;
                int fi = ((y + ky) * 18 + (l15 + kx)) * PXS + q * 8;
                ah[mb] = *(const half8*)&ldsH[fi];
                al[mb] = *(const half8*)&ldsL[fi];
            }
            half8 bh[2], bl[2];
#pragma unroll
            for (int nb = 0; nb < 2; ++nb) {
                int F0 = (nb * 9 + tap) * 2;
                bh[nb] = ((const half8*)wt)[(long)F0 * 64 + lane];
                bl[nb] = ((const half8*)wt)[(long)(F0 + 1) * 64 + lane];
            }
#pragma unroll
            for (int nb = 0; nb < 2; ++nb)
#pragma unroll
                for (int mb = 0; mb < 4; ++mb)
                    accH[mb * 2 + nb] = __builtin_amdgcn_mfma_f32_16x16x32_f16(
                        ah[mb], bh[nb], accH[mb * 2 + nb], 0, 0, 0);
#pragma unroll
            for (int nb = 0; nb < 2; ++nb)
#pragma unroll
                for (int mb = 0; mb < 4; ++mb)
                    accL[mb * 2 + nb] = __builtin_amdgcn_mfma_f32_16x16x32_f16(
                        ah[mb], bl[nb], accL[mb * 2 + nb], 0, 0, 0);
#pragma unroll
            for (int nb = 0; nb < 2; ++nb)
#pragma unroll
                for (int mb = 0; mb < 4; ++mb)
                    accL[mb * 2 + nb] = __builtin_amdgcn_mfma_f32_16x16x32_f16(
                        al[mb], bh[nb], accL[mb * 2 + nb], 0, 0, 0);
        }

    const float inv2048 = 1.0f / 2048.0f;
    float bv[2];
#pragma unroll
    for (int nb = 0; nb < 2; ++nb) bv[nb] = bias[nb * 16 + l15];
    float avg[2] = {0.0f, 0.0f};
#pragma unroll
    for (int k = 0; k < 2; ++k)
#pragma unroll
        for (int j = 0; j < 2; ++j)
#pragma unroll
            for (int nb = 0; nb < 2; ++nb) {
                float m = -1e30f;
#pragma unroll
                for (int dm = 0; dm < 2; ++dm)
#pragma unroll
                    for (int dr = 0; dr < 2; ++dr) {
                        int a = (2 * k + dm) * 2 + nb;
                        int r = 2 * j + dr;
                        float v = accH[a][r] + accL[a][r] * inv2048 + bv[nb];
                        m = fmaxf(m, v);
                    }
                avg[nb] += fmaxf(m, 0.0f);
            }
#pragma unroll
    for (int nb = 0; nb < 2; ++nb) {
        avg[nb] += __shfl_xor(avg[nb], 16);
        avg[nb] += __shfl_xor(avg[nb], 32);
    }
    if (q == 0) {
        red[wv][l15] = avg[0];
        red[wv][16 + l15] = avg[1];
    }
    __syncthreads();
    if (tid < 32) {
        float s = red[0][tid] + red[1][tid] + red[2][tid] + red[3][tid];
        int n = n0 + nl;
        rf[(long)n * 128 + tid * 4 + (tile >> 1) * 2 + (tile & 1)] = s * (1.0f / 64.0f);
    }
}

// ---------------------------------------------------------------------------
// FULLY-FUSED expert: c1(3->32,pool) -> c2(32->64) -> c3(64->64,pool)
// -> c4(64->128) -> c5(128->128) -> GAP.  Grid = E_*B_ blocks
// (e = blockIdx>>10, n = blockIdx&1023), 512 threads (8 waves = 2/SIMD,
// best-measured config).  bufB/bufC at PXS=32 (R7's measured-best layout).
// All intermediates LDS-resident.  LDS pool 155,520 B, time-aliased:
//   region0 [0,25920) f16  : c1-out window -> bufB (c3-out)
//   region1 [25920,77760)  : xs+w1+b1 -> A64 (c2-out) -> bufC (c4-out)
// ---------------------------------------------------------------------------
__launch_bounds__(512, 2)
__global__ void conv_expert(const float* __restrict__ x,
                            const float* __restrict__ w1b, const float* __restrict__ b1b_,
                            const _Float16* __restrict__ wt2b, const float* __restrict__ b2b_,
                            const _Float16* __restrict__ wt3b, const float* __restrict__ b3b_,
                            const _Float16* __restrict__ wt4b, const float* __restrict__ b4b_,
                            const _Float16* __restrict__ wt5b, const float* __restrict__ b5b_,
                            float* __restrict__ featb) {
    __shared__ _Float16 pool[77760];
    _Float16* c2H = pool;                  // [324][40]
    _Float16* c2L = pool + 12960;
    _Float16* BH  = pool;                  // [2][100][32] (alias region0)
    _Float16* BL  = pool + 6400;
    float* xs  = (float*)(pool + 25920);               // 3468 floats
    float* w1s = (float*)(pool + 25920 + 6936);        // 864
    float* b1s = (float*)(pool + 25920 + 6936 + 1728); // 32
    _Float16* AH = pool + 25920;           // [2][324][40]
    _Float16* AL = pool + 51840;
    _Float16* CH = pool + 25920;           // [4][100][32] (alias region1)
    _Float16* CL = pool + 38720;

    const int tid = threadIdx.x;
    const int wv = tid >> 6, lane = tid & 63;
    const int q = lane >> 4, l15 = lane & 15;
    const int rg = wv >> 1, ch2 = wv & 1;
    const int e = blockIdx.x >> 10;
    const int n = blockIdx.x & 1023;
    const float inv2048 = 1.0f / 2048.0f;

    const float* w1 = w1b + e * 864;
    const float* b1 = b1b_ + e * 32;
    const _Float16* wt2 = wt2b + (size_t)e * 36864;
    const float* b2 = b2b_ + e * 64;
    const _Float16* wt3 = wt3b + (size_t)e * 73728;
    const float* b3 = b3b_ + e * 64;
    const _Float16* wt4 = wt4b + (size_t)e * 147456;
    const float* b4 = b4b_ + e * 128;
    const _Float16* wt5 = wt5b + (size_t)e * 294912;
    const float* b5 = b5b_ + e * 128;
    float* feat = featb + (size_t)e * (B_ * 128);

    // ---- P0: zero c1-out window; stage x + c1 weights ----
    {
        half8 z = {};
        half8* zp = (half8*)pool;          // region0 = 3240 half8
        for (int i = tid; i < 3240; i += 512) zp[i] = z;
    }
    for (int i = tid; i < 864; i += 512) w1s[i] = w1[i];
    if (tid < 32) b1s[tid] = b1[tid];
    for (int i = tid; i < 3 * 1156; i += 512) {
        int c = i / 1156;
        int r = i - c * 1156;
        int yy = r / 34 - 1, xx = r % 34 - 1;
        float v = 0.0f;
        if ((unsigned)yy < 32u && (unsigned)xx < 32u)
            v = x[((long)n * 3 + c) * 1024 + yy * 32 + xx];
        xs[i] = v;
    }
    __syncthreads();

    // ---- P1: c1 direct conv + relu + maxpool -> c1-out window interior ----
    {
        const int pix = tid & 255;
        const int py1 = pix >> 4, px1 = pix & 15;
        const int coh = tid >> 8;
#pragma unroll
        for (int cg = 0; cg < 2; ++cg) {
            const int cog = coh * 2 + cg;
            float a[4][8];
#pragma unroll
            for (int j = 0; j < 8; ++j) {
                float bvv = b1s[cog * 8 + j];
#pragma unroll
                for (int p = 0; p < 4; ++p) a[p][j] = bvv;
            }
            for (int ci = 0; ci < 3; ++ci) {
                float patch[16];
#pragma unroll
                for (int r = 0; r < 4; ++r)
#pragma unroll
                    for (int cpx = 0; cpx < 4; ++cpx)
                        patch[r * 4 + cpx] = xs[ci * 1156 + (2 * py1 + r) * 34 + (2 * px1 + cpx)];
#pragma unroll
                for (int ky = 0; ky < 3; ++ky)
#pragma unroll
                    for (int kx = 0; kx < 3; ++kx) {
                        const float* wr = &w1s[((ci * 3 + ky) * 3 + kx) * 32 + cog * 8];
#pragma unroll
                        for (int j = 0; j < 8; ++j) {
                            float wvv = wr[j];
#pragma unroll
                            for (int dy = 0; dy < 2; ++dy)
#pragma unroll
                                for (int dx = 0; dx < 2; ++dx)
                                    a[dy * 2 + dx][j] =
                                        fmaf(patch[(dy + ky) * 4 + (dx + kx)], wvv,
                                             a[dy * 2 + dx][j]);
                        }
                    }
            }
            int fibase = ((py1 + 1) * 18 + (px1 + 1)) * 40 + cog * 8;
#pragma unroll
            for (int j = 0; j < 8; ++j) {
                float m = fmaxf(fmaxf(a[0][j], a[1][j]), fmaxf(a[2][j], a[3][j]));
                m = fmaxf(m, 0.0f);
                _Float16 hi = (_Float16)m;
                _Float16 lo = (_Float16)((m - (float)hi) * 2048.0f);
                c2H[fibase + j] = hi;
                c2L[fibase + j] = lo;
            }
        }
    }
    __syncthreads();

    // ---- P2: zero A64 halo ring (xs/w1s dead); c2 MFMA; epilogue -> A64 ----
    for (int u = tid; u < 2 * 68 * 5; u += 512) {
        int g = u % 5;
        int t2 = u / 5;
        int ck = t2 / 68;
        int rp = t2 % 68;
        int wy, wx;
        if (rp < 18) { wy = 0; wx = rp; }
        else if (rp < 36) { wy = 17; wx = rp - 18; }
        else if (rp < 52) { wy = rp - 35; wx = 0; }
        else { wy = rp - 51; wx = 17; }
        int fi = ck * 12960 + (wy * 18 + wx) * 40 + g * 8;
        *(uint4*)(&AH[fi]) = make_uint4(0, 0, 0, 0);
        *(uint4*)(&AL[fi]) = make_uint4(0, 0, 0, 0);
    }

    f32x4 accH[8], accL[8];
#pragma unroll
    for (int i = 0; i < 8; ++i) { accH[i] = (f32x4){0,0,0,0}; accL[i] = (f32x4){0,0,0,0}; }

#pragma unroll
    for (int ky = 0; ky < 3; ++ky)
#pragma unroll
        for (int kx = 0; kx < 3; ++kx) {
            const int tap = ky * 3 + kx;
            half8 ah[4], al[4];
#pragma unroll
            for (int mb = 0; mb < 4; ++mb) {
                int y = rg * 4 + mb;
                int fi = ((y + ky) * 18 + (l15 + kx)) * 40 + q * 8;
                ah[mb] = *(const half8*)&c2H[fi];
                al[mb] = *(const half8*)&c2L[fi];
            }
            half8 bh[2], bl[2];
#pragma unroll
            for (int nb = 0; nb < 2; ++nb) {
                int nbg = ch2 * 2 + nb;
                int F0 = (nbg * 9 + tap) * 2;
                bh[nb] = ((const half8*)wt2)[(long)F0 * 64 + lane];
                bl[nb] = ((const half8*)wt2)[(long)(F0 + 1) * 64 + lane];
            }
#pragma unroll
            for (int nb = 0; nb < 2; ++nb)
#pragma unroll
                for (int mb = 0; mb < 4; ++mb)
                    accH[mb * 2 + nb] = __builtin_amdgcn_mfma_f32_16x16x32_f16(
                        ah[mb], bh[nb], accH[mb * 2 + nb], 0, 0, 0);
#pragma unroll
            for (int nb = 0; nb < 2; ++nb)
#pragma unroll
                for (int mb = 0; mb < 4; ++mb)
                    accL[mb * 2 + nb] = __builtin_amdgcn_mfma_f32_16x16x32_f16(
                        ah[mb], bl[nb], accL[mb * 2 + nb], 0, 0, 0);
#pragma unroll
            for (int nb = 0; nb < 2; ++nb)
#pragma unroll
                for (int mb = 0; mb < 4; ++mb)
                    accL[mb * 2 + nb] = __builtin_amdgcn_mfma_f32_16x16x32_f16(
                        al[mb], bh[nb], accL[mb * 2 + nb], 0, 0, 0);
        }
    // c2 epilogue: relu -> split fp16 -> A64 interior (chunk = ch2)
    {
        float bv[2];
#pragma unroll
        for (int nb = 0; nb < 2; ++nb) bv[nb] = b2[ch2 * 32 + nb * 16 + l15];
#pragma unroll
        for (int mb = 0; mb < 4; ++mb) {
            int y = rg * 4 + mb;
#pragma unroll
            for (int r = 0; r < 4; ++r) {
                int p = (y + 1) * 18 + (q * 4 + r + 1);
#pragma unroll
                for (int nb = 0; nb < 2; ++nb) {
                    float v = accH[mb * 2 + nb][r] + accL[mb * 2 + nb][r] * inv2048 + bv[nb];
                    v = fmaxf(v, 0.0f);
                    _Float16 hi = (_Float16)v;
                    _Float16 lo = (_Float16)((v - (float)hi) * 2048.0f);
                    int fi = ch2 * 12960 + p * 40 + nb * 16 + l15;
                    AH[fi] = hi;
                    AL[fi] = lo;
                }
            }
        }
    }
    __syncthreads();

    // ---- P3: c3 MFMA (reads A64, 2 chunks, zero staging) ----
#pragma unroll
    for (int i = 0; i < 8; ++i) { accH[i] = (f32x4){0,0,0,0}; accL[i] = (f32x4){0,0,0,0}; }

    for (int c = 0; c < 2; ++c) {
#pragma unroll
        for (int ky = 0; ky < 3; ++ky)
#pragma unroll
            for (int kx = 0; kx < 3; ++kx) {
                const int tap = ky * 3 + kx;
                half8 ah[4], al[4];
#pragma unroll
                for (int mb = 0; mb < 4; ++mb) {
                    int y = rg * 4 + mb;
                    int fi = c * 12960 + ((y + ky) * 18 + (l15 + kx)) * 40 + q * 8;
                    ah[mb] = *(const half8*)&AH[fi];
                    al[mb] = *(const half8*)&AL[fi];
                }
                half8 bh[2], bl[2];
#pragma unroll
                for (int nb = 0; nb < 2; ++nb) {
                    int nbg = ch2 * 2 + nb;
                    int F0 = ((nbg * 9 + tap) * 2 + c) * 2;
                    bh[nb] = ((const half8*)wt3)[(long)F0 * 64 + lane];
                    bl[nb] = ((const half8*)wt3)[(long)(F0 + 1) * 64 + lane];
                }
#pragma unroll
                for (int nb = 0; nb < 2; ++nb)
#pragma unroll
                    for (int mb = 0; mb < 4; ++mb)
                        accH[mb * 2 + nb] = __builtin_amdgcn_mfma_f32_16x16x32_f16(
                            ah[mb], bh[nb], accH[mb * 2 + nb], 0, 0, 0);
#pragma unroll
                for (int nb = 0; nb < 2; ++nb)
#pragma unroll
                    for (int mb = 0; mb < 4; ++mb)
                        accL[mb * 2 + nb] = __builtin_amdgcn_mfma_f32_16x16x32_f16(
                            ah[mb], bl[nb], accL[mb * 2 + nb], 0, 0, 0);
#pragma unroll
                for (int nb = 0; nb < 2; ++nb)
#pragma unroll
                    for (int mb = 0; mb < 4; ++mb)
                        accL[mb * 2 + nb] = __builtin_amdgcn_mfma_f32_16x16x32_f16(
                            al[mb], bh[nb], accL[mb * 2 + nb], 0, 0, 0);
            }
    }
    __syncthreads();   // all A64 reads done (region1 becomes bufC)

    // ---- P4: zero bufB + bufC halo rings; c3 epilogue (maxpool) -> bufB ----
    for (int u = tid; u < 2 * 36 * 4; u += 512) {
        int g = u & 3;
        int t2 = u >> 2;
        int ck = t2 / 36;
        int rp = t2 % 36;
        int wy, wx;
        if (rp < 10) { wy = 0; wx = rp; }
        else if (rp < 20) { wy = 9; wx = rp - 10; }
        else if (rp < 28) { wy = rp - 19; wx = 0; }
        else { wy = rp - 27; wx = 9; }
        int fi = ck * 3200 + (wy * 10 + wx) * 32 + g * 8;
        *(uint4*)(&BH[fi]) = make_uint4(0, 0, 0, 0);
        *(uint4*)(&BL[fi]) = make_uint4(0, 0, 0, 0);
    }
    for (int u = tid; u < 4 * 36 * 4; u += 512) {
        int g = u & 3;
        int t2 = u >> 2;
        int ck = t2 / 36;
        int rp = t2 % 36;
        int wy, wx;
        if (rp < 10) { wy = 0; wx = rp; }
        else if (rp < 20) { wy = 9; wx = rp - 10; }
        else if (rp < 28) { wy = rp - 19; wx = 0; }
        else { wy = rp - 27; wx = 9; }
        int fi = ck * 3200 + (wy * 10 + wx) * 32 + g * 8;
        *(uint4*)(&CH[fi]) = make_uint4(0, 0, 0, 0);
        *(uint4*)(&CL[fi]) = make_uint4(0, 0, 0, 0);
    }
    {
        float bv[2];
#pragma unroll
        for (int nb = 0; nb < 2; ++nb) bv[nb] = b3[ch2 * 32 + nb * 16 + l15];
#pragma unroll
        for (int k = 0; k < 2; ++k)
#pragma unroll
            for (int j = 0; j < 2; ++j) {
                int yy = rg * 2 + k;       // pooled row 0..7
                int xx = q * 2 + j;        // pooled col 0..7
                int p = (yy + 1) * 10 + (xx + 1);
#pragma unroll
                for (int nb = 0; nb < 2; ++nb) {
                    float m = -1e30f;
#pragma unroll
                    for (int dm = 0; dm < 2; ++dm)
#pragma unroll
                        for (int dr = 0; dr < 2; ++dr) {
                            int a = (2 * k + dm) * 2 + nb;
                            int r = 2 * j + dr;
                            float v = accH[a][r] + accL[a][r] * inv2048 + bv[nb];
                            m = fmaxf(m, v);
                        }
                    m = fmaxf(m, 0.0f);
                    _Float16 hi = (_Float16)m;
                    _Float16 lo = (_Float16)((m - (float)hi) * 2048.0f);
                    int fi = ch2 * 3200 + p * 32 + nb * 16 + l15;
                    BH[fi] = hi;
                    BL[fi] = lo;
                }
            }
    }
    __syncthreads();

    // ---- P5: c4 MFMA (reads bufB); epilogue -> bufC interior ----
#pragma unroll
    for (int i = 0; i < 4; ++i) { accH[i] = (f32x4){0,0,0,0}; accL[i] = (f32x4){0,0,0,0}; }

    for (int c = 0; c < 2; ++c) {
#pragma unroll
        for (int ky = 0; ky < 3; ++ky)
#pragma unroll
            for (int kx = 0; kx < 3; ++kx) {
                const int tap = ky * 3 + kx;
                half8 ah[4], al[4];
#pragma unroll
                for (int mb = 0; mb < 4; ++mb) {
                    int m = mb * 16 + l15;
                    int p = ((m >> 3) + ky) * 10 + ((m & 7) + kx);
                    int fi = c * 3200 + p * 32 + q * 8;
                    ah[mb] = *(const half8*)&BH[fi];
                    al[mb] = *(const half8*)&BL[fi];
                }
                half8 bh, bl;
                {
                    int F0 = ((wv * 9 + tap) * 2 + c) * 2;
                    bh = ((const half8*)wt4)[(long)F0 * 64 + lane];
                    bl = ((const half8*)wt4)[(long)(F0 + 1) * 64 + lane];
                }
#pragma unroll
                for (int mb = 0; mb < 4; ++mb)
                    accH[mb] = __builtin_amdgcn_mfma_f32_16x16x32_f16(ah[mb], bh, accH[mb], 0, 0, 0);
#pragma unroll
                for (int mb = 0; mb < 4; ++mb)
                    accL[mb] = __builtin_amdgcn_mfma_f32_16x16x32_f16(ah[mb], bl, accL[mb], 0, 0, 0);
#pragma unroll
                for (int mb = 0; mb < 4; ++mb)
                    accL[mb] = __builtin_amdgcn_mfma_f32_16x16x32_f16(al[mb], bh, accL[mb], 0, 0, 0);
            }
    }
    {
        float bv = b4[wv * 16 + l15];
#pragma unroll
        for (int mb = 0; mb < 4; ++mb)
#pragma unroll
            for (int r = 0; r < 4; ++r) {
                int px = mb * 16 + q * 4 + r;
                int p = ((px >> 3) + 1) * 10 + ((px & 7) + 1);
                float v = accH[mb][r] + accL[mb][r] * inv2048 + bv;
                v = fmaxf(v, 0.0f);
                _Float16 hi = (_Float16)v;
                _Float16 lo = (_Float16)((v - (float)hi) * 2048.0f);
                int fi = (wv >> 1) * 3200 + p * 32 + (wv & 1) * 16 + l15;
                CH[fi] = hi;
                CL[fi] = lo;
            }
    }
    __syncthreads();

    // ---- P6: c5 MFMA (reads bufC, 4 chunks); GAP -> feat ----
#pragma unroll
    for (int i = 0; i < 4; ++i) { accH[i] = (f32x4){0,0,0,0}; accL[i] = (f32x4){0,0,0,0}; }

    for (int c = 0; c < 4; ++c) {
#pragma unroll
        for (int ky = 0; ky < 3; ++ky)
#pragma unroll
            for (int kx = 0; kx < 3; ++kx) {
                const int tap = ky * 3 + kx;
                half8 ah[4], al[4];
#pragma unroll
                for (int mb = 0; mb < 4; ++mb) {
                    int m = mb * 16 + l15;
                    int p = ((m >> 3) + ky) * 10 + ((m & 7) + kx);
                    int fi = c * 3200 + p * 32 + q * 8;
                    ah[mb] = *(const half8*)&CH[fi];
                    al[mb] = *(const half8*)&CL[fi];
                }
                half8 bh, bl;
                {
                    int F0 = ((wv * 9 + tap) * 4 + c) * 2;
                    bh = ((const half8*)wt5)[(long)F0 * 64 + lane];
                    bl = ((const half8*)wt5)[(long)(F0 + 1) * 64 + lane];
                }
#pragma unroll
                for (int mb = 0; mb < 4; ++mb)
                    accH[mb] = __builtin_amdgcn_mfma_f32_16x16x32_f16(ah[mb], bh, accH[mb], 0, 0, 0);
#pragma unroll
                for (int mb = 0; mb < 4; ++mb)
                    accL[mb] = __builtin_amdgcn_mfma_f32_16x16x32_f16(ah[mb], bl, accL[mb], 0, 0, 0);
#pragma unroll
                for (int mb = 0; mb < 4; ++mb)
                    accL[mb] = __builtin_amdgcn_mfma_f32_16x16x32_f16(al[mb], bh, accL[mb], 0, 0, 0);
            }
    }
    {
        float bv = b5[wv * 16 + l15];
        float s = 0.0f;
#pragma unroll
        for (int mb = 0; mb < 4; ++mb)
#pragma unroll
            for (int r = 0; r < 4; ++r) {
                float v = accH[mb][r] + accL[mb][r] * inv2048 + bv;
                s += fmaxf(v, 0.0f);
            }
        s += __shfl_xor(s, 16);
        s += __shfl_xor(s, 32);
        if (lane < 16)
            feat[(long)n * 128 + wv * 16 + l15] = s * (1.0f / 64.0f);
    }
}

// ---------------------------------------------------------------------------
// Expert head (mega-launched over E_*B_ blocks): feat [e][n][128] fp32 ->
// fc1(128,relu) -> fc2(10) -> logitsE [e][n][10].
// ---------------------------------------------------------------------------
__launch_bounds__(128)
__global__ void head_k(const float* __restrict__ featb, const float* __restrict__ fwb,
                       const float* __restrict__ fbb, const float* __restrict__ cwb,
                       const float* __restrict__ cbb, float* __restrict__ outlb) {
    __shared__ float fe[128];
    __shared__ float fv[128];
    int e = blockIdx.x >> 10;
    int n = blockIdx.x & 1023;
    int t = threadIdx.x;
    const float* feat = featb + (size_t)e * (B_ * 128);
    const float* fw = fwb + (size_t)e * 16384;
    const float* fb = fbb + e * 128;
    const float* cw = cwb + (size_t)e * 1280;
    const float* cb = cbb + e * 10;
    float* outl = outlb + (size_t)e * (B_ * 10);

    fe[t] = feat[(long)n * 128 + t];
    __syncthreads();
    const float* wr = fw + t * 128;
    float a = fb[t];
#pragma unroll 8
    for (int k = 0; k < 128; ++k) a = fmaf(fe[k], wr[k], a);
    fv[t] = fmaxf(a, 0.0f);
    __syncthreads();
    if (t < 10) {
        const float* cr = cw + t * 128;
        float a2 = cb[t];
#pragma unroll 8
        for (int k = 0; k < 128; ++k) a2 = fmaf(fv[k], cr[k], a2);
        outl[n * 10 + t] = a2;
    }
}

// FC (trunk)
template <int I, int O, bool RELU>
__global__ void fc_k(const float* __restrict__ in, const float* __restrict__ W,
                     const float* __restrict__ bias, float* __restrict__ out) {
    int g = blockIdx.x * 256 + threadIdx.x;
    if (g >= B_ * O) return;
    int n = g / O;
    int o = g - n * O;
    const float* ip = in + (long)n * I;
    const float* wp = W + (long)o * I;
    float a = bias[o];
#pragma unroll 8
    for (int k = 0; k < I; ++k) a = fmaf(ip[k], wp[k], a);
    if (RELU) a = fmaxf(a, 0.0f);
    out[g] = a;
}

// ---------------------------------------------------------------------------
// conf + balanced + top-2 candidates (one thread per sample).
// ---------------------------------------------------------------------------
__global__ void conf_bal_k(const float* __restrict__ logitsE, const float* __restrict__ gate,
                           const float* __restrict__ ema, float* __restrict__ balanced,
                           unsigned char* __restrict__ cand) {
    int b = blockIdx.x * 256 + threadIdx.x;
    if (b >= B_) return;
    float bal[E_];
#pragma unroll
    for (int e = 0; e < E_; ++e) {
        const float* lp = logitsE + ((long)e * B_ + b) * 10;
        float m = lp[0];
#pragma unroll
        for (int k = 1; k < 10; ++k) m = fmaxf(m, lp[k]);
        float s = 0.0f;
#pragma unroll
        for (int k = 0; k < 10; ++k) s += expf(lp[k] - m);
        float ls = m + logf(s);
        float conf = 0.0f;
#pragma unroll
        for (int k = 0; k < 10; ++k) {
            float pp = expf(lp[k] - ls);
            conf += pp * logf(pp + 1e-12f);
        }
        float em = ema[e];
        float boost = (em < 0.05f) ? (0.05f - em) * 10.0f : 0.0f;
        bal[e] = 0.7f * gate[b * E_ + e] + 0.3f * conf + boost - 2.0f * em;
        balanced[b * E_ + e] = bal[e];
    }
    int i0 = 0;
    float m0 = bal[0];
#pragma unroll
    for (int e = 1; e < E_; ++e)
        if (bal[e] > m0) { m0 = bal[e]; i0 = e; }
    int i1 = -1;
    float m1 = -1e38f;
#pragma unroll
    for (int e = 0; e < E_; ++e)
        if (e != i0 && bal[e] > m1) { m1 = bal[e]; i1 = e; }
    cand[b] = (unsigned char)(i0 | (i1 << 3));
}

// ---------------------------------------------------------------------------
// Sequential greedy capacity dispatch — scalarized.
// ---------------------------------------------------------------------------
__global__ void dispatch_k(const unsigned char* __restrict__ cand, int* __restrict__ chosen) {
    int lane = threadIdx.x;
    unsigned long long L = 0;
    for (int r = 0; r < 16; ++r) {
        unsigned int v = cand[r * 64 + lane];
        int ch = 0;
        for (int q2 = 0; q2 < 64; ++q2) {
            unsigned int s = (unsigned int)__builtin_amdgcn_readlane((int)v, q2);
            unsigned int i0 = s & 7u;
            unsigned int i1 = (s >> 3) & 7u;
            unsigned int a0 = (unsigned int)(L >> (i0 * 10)) & 1023u;
            unsigned int a1 = (unsigned int)(L >> (i1 * 10)) & 1023u;
            unsigned int fb = (a1 < a0) ? i1 : i0;
            unsigned int c = (a0 < 192u) ? i0 : ((a1 < 192u) ? i1 : fb);
            if (lane == q2) ch = (int)c;
            L += 1ull << (c * 10);
        }
        chosen[r * 64 + lane] = ch;
    }
}

__global__ void final_k(const float* __restrict__ logitsE, const int* __restrict__ chosen,
                        float* __restrict__ out) {
    int b = blockIdx.x * 256 + threadIdx.x;
    if (b >= B_) return;
    int c = chosen[b];
    const float w = 1.0f / (1.0f + 1e-12f);
    const float* lp = logitsE + ((long)c * B_ + b) * 10;
#pragma unroll
    for (int k = 0; k < 10; ++k) out[b * 10 + k] = lp[k] * w;
    float* Dp = out + B_ * 10 + B_ * E_ + b * E_;
#pragma unroll
    for (int e = 0; e < E_; ++e) Dp[e] = (e == c) ? 1.0f : 0.0f;
}

// ---------------------------------------------------------------------------
extern "C" void kernel_launch(void* const* d_in, const int* in_sizes, int n_in,
                              void* d_out, int out_size, void* d_ws, size_t ws_size,
                              hipStream_t stream) {
    (void)in_sizes; (void)n_in; (void)out_size; (void)ws_size;
    const float* x     = (const float*)d_in[0];
    const float* t_c1w = (const float*)d_in[1];
    const float* t_b1g = (const float*)d_in[2];
    const float* t_b1b = (const float*)d_in[3];
    const float* t_c2w = (const float*)d_in[4];
    const float* t_b2g = (const float*)d_in[5];
    const float* t_b2b = (const float*)d_in[6];
    const float* t_fcw = (const float*)d_in[7];
    const float* t_fcb = (const float*)d_in[8];
    const float* g1w   = (const float*)d_in[9];
    const float* g1b   = (const float*)d_in[10];
    const float* g2w   = (const float*)d_in[11];
    const float* g2b   = (const float*)d_in[12];
    const float* e_c1w = (const float*)d_in[13];
    const float* e_c1b = (const float*)d_in[14];
    const float* e_b1g = (const float*)d_in[15];
    const float* e_b1b = (const float*)d_in[16];
    const float* e_c2w = (const float*)d_in[17];
    const float* e_c2b = (const float*)d_in[18];
    const float* e_b2g = (const float*)d_in[19];
    const float* e_b2b = (const float*)d_in[20];
    const float* e_c3w = (const float*)d_in[21];
    const float* e_c3b = (const float*)d_in[22];
    const float* e_b3g = (const float*)d_in[23];
    const float* e_b3b = (const float*)d_in[24];
    const float* e_c4w = (const float*)d_in[25];
    const float* e_c4b = (const float*)d_in[26];
    const float* e_b4g = (const float*)d_in[27];
    const float* e_b4b = (const float*)d_in[28];
    const float* e_c5w = (const float*)d_in[29];
    const float* e_c5b = (const float*)d_in[30];
    const float* e_b5g = (const float*)d_in[31];
    const float* e_b5b = (const float*)d_in[32];
    const float* e_fw  = (const float*)d_in[33];
    const float* e_fb  = (const float*)d_in[34];
    const float* e_cw  = (const float*)d_in[35];
    const float* e_cb  = (const float*)d_in[36];
    const float* ema   = (const float*)d_in[37];
    float* out = (float*)d_out;
    float* ws  = (float*)d_ws;

    // workspace layout — ALL offsets in FLOAT units.
    size_t o = 0;
    float* R2f = ws + o; o += 16777216;   // 64 MB (trunk t1 -> t2 staging)
    float* rf_in   = ws + o; o += B_ * 128;
    float* rf      = ws + o; o += B_ * 64;
    float* gv      = ws + o; o += B_ * 32;
    float* gate    = ws + o; o += B_ * E_;
    float* logitsE = ws + o; o += E_ * B_ * 10;
    float* featb   = ws + o; o += (size_t)E_ * B_ * 128;   // GAP output (3 MB)
    int*   chosen  = (int*)(ws + o); o += B_;
    unsigned char* cand = (unsigned char*)(ws + o); o += 256;
    float* wt_t1 = ws + o; o += 864;
    float* bt_t1 = ws + o; o += 32;
    float* bt_t2 = ws + o; o += 32;
    float* wt_c1 = ws + o; o += 6 * 864;
    float* bt_c1 = ws + o; o += 6 * 32;
    float* bt_c2 = ws + o; o += 6 * 64;
    float* bt_c3 = ws + o; o += 6 * 64;
    float* bt_c4 = ws + o; o += 6 * 128;
    float* bt_c5 = ws + o; o += 6 * 128;
    _Float16* wfrag_t2 = (_Float16*)(ws + o); o += 9216;
    _Float16* wfrag_c2 = (_Float16*)(ws + o); o += 110592;
    _Float16* wfrag_c3 = (_Float16*)(ws + o); o += 221184;
    _Float16* wfrag_c4 = (_Float16*)(ws + o); o += 442368;
    _Float16* wfrag_c5 = (_Float16*)(ws + o); o += 884736;

    unsigned int* R2u = (unsigned int*)R2f;

    auto gsz = [](int n) { return (n + 255) / 256; };
    // ---- weight prep ----
    prep_w<<<gsz(864), 256, 0, stream>>>(t_c1w, t_b1g, wt_t1, 32, 3, 864);
    prep_b<<<1, 256, 0, stream>>>(nullptr, t_b1g, t_b1b, bt_t1, 32);
    prep_wfrag<<<gsz(9216), 256, 0, stream>>>(t_c2w, t_b2g, wfrag_t2, 32, 32, 9216);
    prep_b<<<1, 256, 0, stream>>>(nullptr, t_b2g, t_b2b, bt_t2, 32);
    prep_w<<<gsz(5184), 256, 0, stream>>>(e_c1w, e_b1g, wt_c1, 32, 3, 5184);
    prep_b<<<1, 256, 0, stream>>>(e_c1b, e_b1g, e_b1b, bt_c1, 192);
    prep_wfrag<<<gsz(110592), 256, 0, stream>>>(e_c2w, e_b2g, wfrag_c2, 32, 64, 110592);
    prep_b<<<2, 256, 0, stream>>>(e_c2b, e_b2g, e_b2b, bt_c2, 384);
    prep_wfrag<<<gsz(221184), 256, 0, stream>>>(e_c3w, e_b3g, wfrag_c3, 64, 64, 221184);
    prep_b<<<2, 256, 0, stream>>>(e_c3b, e_b3g, e_b3b, bt_c3, 384);
    prep_wfrag<<<gsz(442368), 256, 0, stream>>>(e_c4w, e_b4g, wfrag_c4, 64, 128, 442368);
    prep_b<<<3, 256, 0, stream>>>(e_c4b, e_b4g, e_b4b, bt_c4, 768);
    prep_wfrag<<<gsz(884736), 256, 0, stream>>>(e_c5w, e_b5g, wfrag_c5, 128, 128, 884736);
    prep_b<<<3, 256, 0, stream>>>(e_c5b, e_b5g, e_b5b, bt_c5, 768);

    // ---- routing trunk (2 batch-halves; t1 -> packed NHWC in R2) ----
    for (int q = 0; q < 2; ++q) {
        const float* xq = x + (size_t)q * 512 * 3 * 1024;
        conv3x3<3, 32, 32, 16, 32, 3, false, 1><<<512 * 4, 256, 0, stream>>>(
            xq, wt_t1, bt_t1, (void*)R2u);
        conv_mfma_t2<<<512 * 4, 256, 0, stream>>>(R2u, wfrag_t2, bt_t2, rf_in, q * 512);
    }
    fc_k<128, 64, true><<<256, 256, 0, stream>>>(rf_in, t_fcw, t_fcb, rf);
    fc_k<64, 32, true><<<128, 256, 0, stream>>>(rf, g1w, g1b, gv);
    fc_k<32, 6, false><<<24, 256, 0, stream>>>(gv, g2w, g2b, gate);

    // ---- experts: fully fused c1..c5+GAP, all 6 experts in ONE launch ----
    conv_expert<<<E_ * B_, 512, 0, stream>>>(
        x, wt_c1, bt_c1, wfrag_c2, bt_c2, wfrag_c3, bt_c3,
        wfrag_c4, bt_c4, wfrag_c5, bt_c5, featb);
    head_k<<<E_ * B_, 128, 0, stream>>>(featb, e_fw, e_fb, e_cw, e_cb, logitsE);

    // ---- scoring, dispatch, combine ----
    float* balanced = out + B_ * 10;
    conf_bal_k<<<4, 256, 0, stream>>>(logitsE, gate, ema, balanced, cand);
    dispatch_k<<<1, 64, 0, stream>>>(cand, chosen);
    final_k<<<4, 256, 0, stream>>>(logitsE, chosen, out);
}